// Round 8
// baseline (457.660 us; speedup 1.0000x reference)
//
#include <hip/hip_runtime.h>
#include <hip/hip_bf16.h>

constexpr int N    = 8192;
constexpr int FIN  = 512;
constexpr int FOUT = 64;
constexpr int NSPLIT = 8;            // j-split across blocks (1024 blocks, all resident)
constexpr int JCHUNK = N / NSPLIT;   // 1024 j per block
constexpr int NSLICE = 8;            // B-staging slices per block
constexpr int JS     = JCHUNK / NSLICE;  // 128 j per B slice
constexpr int LROW   = JS + 8;       // LDS B row pitch in bf16 (136 shorts)

typedef __attribute__((ext_vector_type(8))) short short8;
typedef __attribute__((ext_vector_type(4))) float f32x4;

union BF2U { unsigned int u; __hip_bfloat162 h; };

// ---------------------------------------------------------------------------
// Kernel 1: h = input @ W (fp32), fused epilogue:
//   E1=exp(s1), F1=exp(0.2 s1), E2=exp(s2), F2=exp(0.2 s2)  (exp-free k2)
//   + bf16 h^T write (B-operand feed for MFMA).
// ---------------------------------------------------------------------------
__global__ __launch_bounds__(256) void k1_proj(
    const float* __restrict__ input, const float* __restrict__ W,
    const float* __restrict__ a, __hip_bfloat16* __restrict__ hbT,
    float* __restrict__ E1, float* __restrict__ F1,
    float* __restrict__ E2, float* __restrict__ F2)
{
    __shared__ __hip_bfloat16 tile[8][64];
    const int tid  = threadIdx.x;
    const int col  = tid & 63;
    const int g    = tid >> 6;
    const int rbase = blockIdx.x * 8;

    float acc[2] = {0.f, 0.f};
    const float* in0 = input + (size_t)(rbase + g * 2) * FIN;

    for (int k = 0; k < FIN; k += 8) {
        float w[8];
        #pragma unroll
        for (int q = 0; q < 8; ++q) w[q] = W[(k + q) * FOUT + col];
        const float4 x0a = *(const float4*)(in0 + 0 * FIN + k);
        const float4 x0b = *(const float4*)(in0 + 0 * FIN + k + 4);
        const float4 x1a = *(const float4*)(in0 + 1 * FIN + k);
        const float4 x1b = *(const float4*)(in0 + 1 * FIN + k + 4);
        acc[0] = fmaf(x0a.w, w[3], fmaf(x0a.z, w[2], fmaf(x0a.y, w[1], fmaf(x0a.x, w[0], acc[0]))));
        acc[0] = fmaf(x0b.w, w[7], fmaf(x0b.z, w[6], fmaf(x0b.y, w[5], fmaf(x0b.x, w[4], acc[0]))));
        acc[1] = fmaf(x1a.w, w[3], fmaf(x1a.z, w[2], fmaf(x1a.y, w[1], fmaf(x1a.x, w[0], acc[1]))));
        acc[1] = fmaf(x1b.w, w[7], fmaf(x1b.z, w[6], fmaf(x1b.y, w[5], fmaf(x1b.x, w[4], acc[1]))));
    }

    const float a1c = a[col];
    const float a2c = a[FOUT + col];
    #pragma unroll
    for (int q = 0; q < 2; ++q) {
        float r1 = acc[q] * a1c;
        float r2 = acc[q] * a2c;
        #pragma unroll
        for (int off = 32; off >= 1; off >>= 1) {
            r1 += __shfl_xor(r1, off, 64);
            r2 += __shfl_xor(r2, off, 64);
        }
        if (col == 0) {
            const int i = rbase + g * 2 + q;
            E1[i] = __expf(r1);
            F1[i] = __expf(0.2f * r1);
            E2[i] = __expf(r2);
            F2[i] = __expf(0.2f * r2);
        }
        tile[g * 2 + q][col] = __float2bfloat16(acc[q]);
    }
    __syncthreads();

    if (tid < 128) {
        const int c = tid >> 1, part = tid & 1;
        unsigned short v[4];
        #pragma unroll
        for (int u = 0; u < 4; ++u) {
            __hip_bfloat16 hv = tile[part * 4 + u][c];
            v[u] = *reinterpret_cast<unsigned short*>(&hv);
        }
        *(ushort4*)((unsigned short*)hbT + (size_t)c * N + rbase + part * 4) =
            make_ushort4(v[0], v[1], v[2], v[3]);
    }
}

// ---------------------------------------------------------------------------
// Kernel 2: attention + PV via MFMA. R8:
//  - adj staged ONCE per block as full 4 KB-contiguous row extents (64 rows),
//    bit-packed into an 8.4 KB LDS mask up front. With all 8 s-groups resident
//    the chip's concurrent adj windows cover the ENTIRE 32 KB row pitch ->
//    all HBM channels active (fix for the power-of-2-stride channel aliasing
//    that capped adj delivery at ~1.7 TB/s through R7).
//  - B/E2/F2 stream from L2 in 8 slices of 128 j (Bl 17.4 KB; LDS total 33.3 KB,
//    4 blocks/CU, grid fully resident).
//  - inner loop: exp-free p = max(E1i*E2j, F1i*F2j), packed bf16 cvt,
//    denominator via 5th MFMA against all-ones B.
// ---------------------------------------------------------------------------
__global__ __launch_bounds__(256, 4) void k2_attn(
    const int* __restrict__ adj,
    const float* __restrict__ E1, const float* __restrict__ F1,
    const float* __restrict__ E2, const float* __restrict__ F2,
    const unsigned short* __restrict__ hbT,
    float* __restrict__ pAcc, float* __restrict__ pZ)
{
    __shared__ unsigned short Bl[64 * LROW];   // 17.4 KB, padded rows
    __shared__ unsigned int   Ml[64 * 33];     // 8.4 KB: 32 u32/row + 1 pad word
    __shared__ float          E2l[JCHUNK];     // 4 KB
    __shared__ float          F2l[JCHUNK];     // 4 KB

    const int r   = blockIdx.x;
    const int s   = blockIdx.y;
    const int tid = threadIdx.x;
    const int w     = tid >> 6;
    const int lane  = tid & 63;
    const int row16 = lane & 15;
    const int quad  = lane >> 4;
    const int jcbeg = s * JCHUNK;

    // ---- stage E2/F2 for the whole chunk (1024 floats each) ----
    *(float4*)(&E2l[tid * 4]) = *(const float4*)(E2 + jcbeg + tid * 4);
    *(float4*)(&F2l[tid * 4]) = *(const float4*)(F2 + jcbeg + tid * 4);

    // ---- stage & pack ALL adj for this block: 64 rows x 4 KB contiguous ----
    // wave w owns rows w*16..+15; per (row,u): lane loads int4 (1 KB/instr,
    // 4 instrs = 4 KB sequential per row). Pack: nibble -> byte via lane-pair
    // shfl; even lanes write Mlb[row][u*32 + lane/2].
    {
        unsigned char* Mlb = (unsigned char*)Ml;   // row pitch 132 bytes
        #pragma unroll 4
        for (int rr = 0; rr < 16; ++rr) {
            const int rloc = w * 16 + rr;
            const int* rowp = adj + (size_t)(r * 64 + rloc) * N + jcbeg;
            #pragma unroll
            for (int u = 0; u < 4; ++u) {
                const int4 av = *(const int4*)(rowp + u * 256 + lane * 4);
                unsigned int nib =
                    (av.x != 0 ? 1u : 0u) | (av.y != 0 ? 2u : 0u) |
                    (av.z != 0 ? 4u : 0u) | (av.w != 0 ? 8u : 0u);
                const unsigned int other = __shfl_xor(nib, 1, 64);
                if (!(lane & 1))
                    Mlb[rloc * 132 + u * 32 + (lane >> 1)] =
                        (unsigned char)(nib | (other << 4));
            }
        }
    }
    __syncthreads();

    const int iloc = w * 16 + row16;
    const int i    = r * 64 + iloc;
    const float E1i = E1[i];
    const float F1i = F1[i];

    short8 ones;
    #pragma unroll
    for (int q = 0; q < 8; ++q) ones[q] = (short)0x3F80;   // bf16 1.0

    f32x4 acc0 = {0.f, 0.f, 0.f, 0.f};
    f32x4 acc1 = {0.f, 0.f, 0.f, 0.f};
    f32x4 acc2 = {0.f, 0.f, 0.f, 0.f};
    f32x4 acc3 = {0.f, 0.f, 0.f, 0.f};
    f32x4 accz = {0.f, 0.f, 0.f, 0.f};

    for (int sl = 0; sl < NSLICE; ++sl) {
        // ---- stage B slice: 64 feature rows x 128 bf16 (from L2-resident hbT)
        #pragma unroll
        for (int rr = 0; rr < 4; ++rr) {
            const int seg = rr * 256 + tid;        // [0, 1024) 16B-segments
            const int f = seg >> 4, o = seg & 15;
            const short8 v = *(const short8*)((const short*)hbT +
                               (size_t)f * N + jcbeg + sl * JS + o * 8);
            *(short8*)(&Bl[f * LROW + o * 8]) = v;
        }
        __syncthreads();

        #pragma unroll
        for (int it = 0; it < JS / 32; ++it) {     // 4 iterations
            const int jj  = it * 32 + quad * 8;    // j rel. to slice
            const int jja = sl * JS + jj;          // j rel. to chunk

            const unsigned int mword = Ml[iloc * 33 + sl * 4 + it];
            const unsigned int mbyte = (mword >> (8 * quad)) & 0xffu;

            const float4 eA = *(const float4*)(&E2l[jja]);
            const float4 eB = *(const float4*)(&E2l[jja + 4]);
            const float4 fA = *(const float4*)(&F2l[jja]);
            const float4 fB = *(const float4*)(&F2l[jja + 4]);

            const short8 b0 = *(const short8*)(&Bl[(row16 +  0) * LROW + jj]);
            const short8 b1 = *(const short8*)(&Bl[(row16 + 16) * LROW + jj]);
            const short8 b2 = *(const short8*)(&Bl[(row16 + 32) * LROW + jj]);
            const short8 b3 = *(const short8*)(&Bl[(row16 + 48) * LROW + jj]);

            float e2v[8], f2v[8];
            e2v[0] = eA.x; e2v[1] = eA.y; e2v[2] = eA.z; e2v[3] = eA.w;
            e2v[4] = eB.x; e2v[5] = eB.y; e2v[6] = eB.z; e2v[7] = eB.w;
            f2v[0] = fA.x; f2v[1] = fA.y; f2v[2] = fA.z; f2v[3] = fA.w;
            f2v[4] = fB.x; f2v[5] = fB.y; f2v[6] = fB.z; f2v[7] = fB.w;

            float pv[8];
            #pragma unroll
            for (int j = 0; j < 8; ++j) {
                // exp(leakyrelu(s1+s2)) == max(E1*E2, F1*F2) exactly
                float p = fmaxf(E1i * e2v[j], F1i * f2v[j]);
                pv[j] = ((mbyte >> j) & 1u) ? p : 0.f;
            }

            short8 afrag;
            #pragma unroll
            for (int jp = 0; jp < 4; ++jp) {       // packed bf16 cvt (RNE)
                BF2U cv;
                cv.h = __float22bfloat162_rn(make_float2(pv[2 * jp], pv[2 * jp + 1]));
                afrag[2 * jp]     = (short)(cv.u & 0xffffu);
                afrag[2 * jp + 1] = (short)(cv.u >> 16);
            }

            acc0 = __builtin_amdgcn_mfma_f32_16x16x32_bf16(afrag, b0, acc0, 0, 0, 0);
            acc1 = __builtin_amdgcn_mfma_f32_16x16x32_bf16(afrag, b1, acc1, 0, 0, 0);
            acc2 = __builtin_amdgcn_mfma_f32_16x16x32_bf16(afrag, b2, acc2, 0, 0, 0);
            acc3 = __builtin_amdgcn_mfma_f32_16x16x32_bf16(afrag, b3, acc3, 0, 0, 0);
            accz = __builtin_amdgcn_mfma_f32_16x16x32_bf16(afrag, ones, accz, 0, 0, 0);
        }
        __syncthreads();   // Bl reuse safety before next slice restage
    }

    // z epilogue: D row m = quad*4+reg (duplicated across the 16 col-lanes)
    if (row16 == 0) {
        #pragma unroll
        for (int reg = 0; reg < 4; ++reg)
            pZ[(size_t)s * N + r * 64 + w * 16 + quad * 4 + reg] = accz[reg];
    }

    // out-tile: C/D layout col=lane&15, row=quad*4+reg
    float* outp = pAcc + ((size_t)s * N + (size_t)r * 64 + w * 16) * FOUT;
    #pragma unroll
    for (int reg = 0; reg < 4; ++reg) {
        const int row = quad * 4 + reg;
        outp[row * FOUT + ( 0 + row16)] = acc0[reg];
        outp[row * FOUT + (16 + row16)] = acc1[reg];
        outp[row * FOUT + (32 + row16)] = acc2[reg];
        outp[row * FOUT + (48 + row16)] = acc3[reg];
    }
}

// ---------------------------------------------------------------------------
// Kernel 3: out[i][f] = sum_s pAcc[s][i][f] / sum_s pZ[s][i]
// ---------------------------------------------------------------------------
__global__ __launch_bounds__(256) void k3_combine(
    const float* __restrict__ pAcc, const float* __restrict__ pZ,
    float* __restrict__ out)
{
    const int idx = blockIdx.x * 256 + threadIdx.x;
    const int i = idx >> 6;
    float num = 0.f, den = 0.f;
    #pragma unroll
    for (int s = 0; s < NSPLIT; ++s) {
        num += pAcc[(size_t)s * N * FOUT + idx];
        den += pZ[(size_t)s * N + i];
    }
    out[idx] = num / den;
}

// ---------------------------------------------------------------------------
extern "C" void kernel_launch(void* const* d_in, const int* in_sizes, int n_in,
                              void* d_out, int out_size, void* d_ws, size_t ws_size,
                              hipStream_t stream)
{
    const float* input = (const float*)d_in[0];
    const int*   adj   = (const int*)d_in[1];
    const float* W     = (const float*)d_in[2];
    const float* a     = (const float*)d_in[3];
    float* out = (float*)d_out;

    char* ws = (char*)d_ws;
    __hip_bfloat16* hbT = (__hip_bfloat16*)ws;               // 1 MB
    float* E1   = (float*)(ws + (size_t)FOUT * N * 2);       // 32 KB
    float* F1   = E1 + N;                                    // 32 KB
    float* E2   = F1 + N;                                    // 32 KB
    float* F2   = E2 + N;                                    // 32 KB
    float* pZ   = F2 + N;                                    // NSPLIT*N*4 = 256 KB
    float* pAcc = pZ + (size_t)NSPLIT * N;                   // 16.8 MB

    k1_proj<<<N / 8, 256, 0, stream>>>(input, W, a, hbT, E1, F1, E2, F2);

    dim3 g2(N / 64, NSPLIT);
    k2_attn<<<g2, 256, 0, stream>>>(adj, E1, F1, E2, F2,
                                    (const unsigned short*)hbT, pAcc, pZ);

    k3_combine<<<(N * FOUT) / 256, 256, 0, stream>>>(pAcc, pZ, out);
}